// Round 3
// baseline (124.041 us; speedup 1.0000x reference)
//
#include <hip/hip_runtime.h>
#include <math.h>

#define ALPHA_C (-0.01f)
#define WPW 11              // windows resolved per wave (= per block)
#define SPAN_F 3072         // floats staged per wave (12 KB)
#define ROUNDS 12           // 12 x (64 lanes x 16 B) = 12 KB async stages

typedef __attribute__((address_space(3))) unsigned char* lds_ptr_t;
typedef const __attribute__((address_space(1))) unsigned char* gbl_ptr_t;

// One wave per workgroup; no barriers anywhere. LDS/block = 14 KB -> 11 blocks/CU.
__global__ __launch_bounds__(64, 3)
void softmin_dtw_kernel(const float* __restrict__ x, const float* __restrict__ S,
                        float* __restrict__ partials, long long Q, int W) {
  __shared__ __align__(16) float sX[SPAN_F];   // this wave's x span
  __shared__ __align__(16) float sS[512];      // this wave's S copy (L2-hot src)

  const int lane = threadIdx.x;                 // blockDim == 64
  const long long gw = blockIdx.x;              // global wave id
  const long long w0 = gw * WPW;                // first window of this wave
  const long long b0 = w0 * 250LL;              // first float of the span
  const bool wave_active = (w0 < (long long)W);

  // ---- async staging: direct global->LDS, all issued back-to-back ----
  if (wave_active) {
    #pragma unroll
    for (int r = 0; r < ROUNDS; ++r) {
      const long long gp = b0 + 256LL * r + 4LL * lane;   // float index
      if (b0 + 256LL * (r + 1) <= Q) {
        __builtin_amdgcn_global_load_lds(
            (gbl_ptr_t)(const void*)(x + gp),
            (lds_ptr_t)(void*)(&sX[256 * r]),
            16, 0, 0);
      } else {
        float4 v;
        v.x = (gp     < Q) ? x[gp]     : 0.f;
        v.y = (gp + 1 < Q) ? x[gp + 1] : 0.f;
        v.z = (gp + 2 < Q) ? x[gp + 2] : 0.f;
        v.w = (gp + 3 < Q) ? x[gp + 3] : 0.f;
        *reinterpret_cast<float4*>(&sX[256 * r + 4 * lane]) = v;
      }
    }
  }
  // S copy: 500 floats = 125 float4 slots; round0 = 64 lanes, round1 = lanes 0..60
  __builtin_amdgcn_global_load_lds((gbl_ptr_t)(const void*)(S + 4 * lane),
                                   (lds_ptr_t)(void*)(&sS[0]), 16, 0, 0);
  if (lane < 61)
    __builtin_amdgcn_global_load_lds((gbl_ptr_t)(const void*)(S + 256 + 4 * lane),
                                     (lds_ptr_t)(void*)(&sS[256]), 16, 0, 0);

  // ---- yy[j]: lanes 0..4, straight from global S (L2-hot), overlaps staging ----
  float yyv = 0.f;
  if (lane < 5) {
    const float* sp = S + 100 * lane;
    #pragma unroll
    for (int s = 0; s < 100; s += 4) {
      const float4 v = *reinterpret_cast<const float4*>(&sp[s]);
      yyv = fmaf(v.x, v.x, fmaf(v.y, v.y, fmaf(v.z, v.z, fmaf(v.w, v.w, yyv))));
    }
  }

  // Wave-level drain of this wave's global_load_lds (no workgroup barrier needed:
  // nobody else touches this block's LDS).
  asm volatile("s_waitcnt vmcnt(0)" ::: "memory");

  const float yy0 = __shfl(yyv, 0);
  const float yy1 = __shfl(yyv, 1);
  const float yy2 = __shfl(yyv, 2);
  const float yy3 = __shfl(yyv, 3);
  const float yy4 = __shfl(yyv, 4);

  // ---- per-chunk partial dots (chunk = lane; lanes >=60 duplicate chunk 59) ----
  const int cc = (lane < 60) ? lane : 59;
  const int i0 = (3 * cc) % 5;        // even-position segment row
  const int i1 = (i0 + 2) % 5;        // odd-position segment row
  const int a0 = (i0 > 0 ? i0 - 1 : 0) * 100;
  const int a1 = i0 * 100;
  const int a2 = (i0 < 4 ? i0 + 1 : 4) * 100;
  const int e0 = (i1 > 0 ? i1 - 1 : 0) * 100 + 50;
  const int e1 = i1 * 100 + 50;
  const int e2 = (i1 < 4 ? i1 + 1 : 4) * 100 + 50;

  float sq = 0.f, A0 = 0.f, A1 = 0.f, A2 = 0.f, B0 = 0.f, B1 = 0.f, B2 = 0.f;
  const float* xc = &sX[cc * 50];
  #pragma unroll 5
  for (int t = 0; t < 50; t += 2) {
    const float2 xv = *reinterpret_cast<const float2*>(&xc[t]);
    float2 y;
    sq = fmaf(xv.x, xv.x, fmaf(xv.y, xv.y, sq));
    y = *reinterpret_cast<const float2*>(&sS[a0 + t]);
    A0 = fmaf(xv.x, y.x, fmaf(xv.y, y.y, A0));
    y = *reinterpret_cast<const float2*>(&sS[a1 + t]);
    A1 = fmaf(xv.x, y.x, fmaf(xv.y, y.y, A1));
    y = *reinterpret_cast<const float2*>(&sS[a2 + t]);
    A2 = fmaf(xv.x, y.x, fmaf(xv.y, y.y, A2));
    y = *reinterpret_cast<const float2*>(&sS[e0 + t]);
    B0 = fmaf(xv.x, y.x, fmaf(xv.y, y.y, B0));
    y = *reinterpret_cast<const float2*>(&sS[e1 + t]);
    B1 = fmaf(xv.x, y.x, fmaf(xv.y, y.y, B1));
    y = *reinterpret_cast<const float2*>(&sS[e2 + t]);
    B2 = fmaf(xv.x, y.x, fmaf(xv.y, y.y, B2));
  }

  // ---- neighbor combine via shfl (odd chunk c+1 supplies sq/B*) ----
  const float nsq = __shfl_down(sq, 1);
  const float nB0 = __shfl_down(B0, 1);
  const float nB1 = __shfl_down(B1, 1);
  const float nB2 = __shfl_down(B2, 1);

  const float cell_xx = sq + nsq;   // xx of segment row i0 (both halves)
  const float cell_p  = A0 + nB0;   // xy(i0, i0-1)
  const float cell_m  = A1 + nB1;   // xy(i0, i0)
  const float cell_n  = A2 + nB2;   // xy(i0, i0+1)

  // ---- gather band rows to window-owner lane via shfl ----
  float r_xx[5], r_p[5], r_m[5], r_n[5];
  #pragma unroll
  for (int i = 0; i < 5; ++i) {
    const int src = 5 * lane + 2 * i;   // <=58 for lane<11; garbage otherwise
    r_xx[i] = __shfl(cell_xx, src);
    r_p[i]  = __shfl(cell_p, src);
    r_m[i]  = __shfl(cell_m, src);
    r_n[i]  = __shfl(cell_n, src);
  }

  // ---- banded DTW + exp, one window per lane (lanes 0..10) ----
  float xi = 0.f;
  if (lane < WPW && w0 + lane < (long long)W) {
    const float C00 = r_xx[0] + yy0 - 2.f * r_m[0];
    const float C01 = r_xx[0] + yy1 - 2.f * r_n[0];
    const float C10 = r_xx[1] + yy0 - 2.f * r_p[1];
    const float C11 = r_xx[1] + yy1 - 2.f * r_m[1];
    const float C12 = r_xx[1] + yy2 - 2.f * r_n[1];
    const float C21 = r_xx[2] + yy1 - 2.f * r_p[2];
    const float C22 = r_xx[2] + yy2 - 2.f * r_m[2];
    const float C23 = r_xx[2] + yy3 - 2.f * r_n[2];
    const float C32 = r_xx[3] + yy2 - 2.f * r_p[3];
    const float C33 = r_xx[3] + yy3 - 2.f * r_m[3];
    const float C34 = r_xx[3] + yy4 - 2.f * r_n[3];
    const float C43 = r_xx[4] + yy3 - 2.f * r_p[4];
    const float C44 = r_xx[4] + yy4 - 2.f * r_m[4];

    const float c11v = C00;
    const float c12v = C01 + c11v;
    const float c21v = C10 + c11v;
    const float c22v = C11 + fminf(fminf(c12v, c21v), c11v);
    const float c23v = C12 + fminf(c22v, c12v);
    const float c32v = C21 + fminf(c22v, c21v);
    const float c33v = C22 + fminf(fminf(c23v, c32v), c22v);
    const float c34v = C23 + fminf(c33v, c23v);
    const float c43v = C32 + fminf(c33v, c32v);
    const float c44v = C33 + fminf(fminf(c34v, c43v), c33v);
    const float c45v = C34 + fminf(c44v, c34v);
    const float c54v = C43 + fminf(c44v, c43v);
    const float c55v = C44 + fminf(fminf(c45v, c54v), c44v);

    xi = expf(ALPHA_C * sqrtf(fmaxf(c55v, 0.f)));
  }

  // ---- wave reduce, ONE plain store per wave (no barrier, no atomic) ----
  #pragma unroll
  for (int off = 32; off > 0; off >>= 1) xi += __shfl_down(xi, off);
  if (lane == 0) partials[gw] = xi;
}

__global__ __launch_bounds__(256)
void reduce_partials(const float* __restrict__ partials, float* __restrict__ out,
                     int n, float inv_W) {
  __shared__ float sR[4];
  const int tid = threadIdx.x;
  float a = 0.f;
  for (int i = tid; i < n; i += 256) a += partials[i];
  #pragma unroll
  for (int off = 32; off > 0; off >>= 1) a += __shfl_down(a, off);
  if ((tid & 63) == 0) sR[tid >> 6] = a;
  __syncthreads();
  if (tid == 0) out[0] = (sR[0] + sR[1] + sR[2] + sR[3]) * inv_W;
}

extern "C" void kernel_launch(void* const* d_in, const int* in_sizes, int n_in,
                              void* d_out, int out_size, void* d_ws, size_t ws_size,
                              hipStream_t stream) {
  const float* x = (const float*)d_in[0];
  const float* S = (const float*)d_in[1];
  float* out = (float*)d_out;
  float* partials = (float*)d_ws;

  const long long Q = in_sizes[0];
  const int L = in_sizes[1];   // 500
  const int step = L / 2;      // 250
  const long long n = Q - L;
  const int W = (int)((n + step - 1) / step);  // 79998

  const int waves = (W + WPW - 1) / WPW;       // 7273 blocks (1 wave each)

  softmin_dtw_kernel<<<waves, 64, 0, stream>>>(x, S, partials, Q, W);
  reduce_partials<<<1, 256, 0, stream>>>(partials, out, waves,
                                         1.0f / (float)W);
}

// Round 4
// 120.168 us; speedup vs baseline: 1.0322x; 1.0322x over previous
//
#include <hip/hip_runtime.h>
#include <math.h>

#define ALPHA_C (-0.01f)
#define WPW 11              // windows per span
#define SPAN_F 3072         // floats staged per span (12 KB)
#define ROUNDS 12           // 12 x (64 lanes x 16 B) per span
#define NBLK 1536           // persistent 1-wave blocks: 6 per CU (26 KB LDS each)

typedef __attribute__((address_space(3))) unsigned char* lds_ptr_t;
typedef const __attribute__((address_space(1))) unsigned char* gbl_ptr_t;

// Per-span compute: partial dots from LDS, shfl combine, banded DTW, exp.
// Returns xi for window-owner lanes (0 for others / out-of-range windows).
__device__ __forceinline__ float span_body(const float* xb, const float* sS,
                                           float yy0, float yy1, float yy2,
                                           float yy3, float yy4, int lane,
                                           long long w0, int W) {
  const int cc = (lane < 60) ? lane : 59;
  const int i0 = (3 * cc) % 5;        // even-position segment row
  const int i1 = (i0 + 2) % 5;        // odd-position segment row
  const int a0 = (i0 > 0 ? i0 - 1 : 0) * 100;
  const int a1 = i0 * 100;
  const int a2 = (i0 < 4 ? i0 + 1 : 4) * 100;
  const int e0 = (i1 > 0 ? i1 - 1 : 0) * 100 + 50;
  const int e1 = i1 * 100 + 50;
  const int e2 = (i1 < 4 ? i1 + 1 : 4) * 100 + 50;

  float sq = 0.f, A0 = 0.f, A1 = 0.f, A2 = 0.f, B0 = 0.f, B1 = 0.f, B2 = 0.f;
  const float* xc = &xb[cc * 50];
  #pragma unroll 5
  for (int t = 0; t < 50; t += 2) {
    const float2 xv = *reinterpret_cast<const float2*>(&xc[t]);
    float2 y;
    sq = fmaf(xv.x, xv.x, fmaf(xv.y, xv.y, sq));
    y = *reinterpret_cast<const float2*>(&sS[a0 + t]);
    A0 = fmaf(xv.x, y.x, fmaf(xv.y, y.y, A0));
    y = *reinterpret_cast<const float2*>(&sS[a1 + t]);
    A1 = fmaf(xv.x, y.x, fmaf(xv.y, y.y, A1));
    y = *reinterpret_cast<const float2*>(&sS[a2 + t]);
    A2 = fmaf(xv.x, y.x, fmaf(xv.y, y.y, A2));
    y = *reinterpret_cast<const float2*>(&sS[e0 + t]);
    B0 = fmaf(xv.x, y.x, fmaf(xv.y, y.y, B0));
    y = *reinterpret_cast<const float2*>(&sS[e1 + t]);
    B1 = fmaf(xv.x, y.x, fmaf(xv.y, y.y, B1));
    y = *reinterpret_cast<const float2*>(&sS[e2 + t]);
    B2 = fmaf(xv.x, y.x, fmaf(xv.y, y.y, B2));
  }

  // neighbor combine via shfl (odd chunk c+1 supplies sq/B*)
  const float nsq = __shfl_down(sq, 1);
  const float nB0 = __shfl_down(B0, 1);
  const float nB1 = __shfl_down(B1, 1);
  const float nB2 = __shfl_down(B2, 1);

  const float cell_xx = sq + nsq;
  const float cell_p  = A0 + nB0;
  const float cell_m  = A1 + nB1;
  const float cell_n  = A2 + nB2;

  float r_xx[5], r_p[5], r_m[5], r_n[5];
  #pragma unroll
  for (int i = 0; i < 5; ++i) {
    const int src = 5 * lane + 2 * i;
    r_xx[i] = __shfl(cell_xx, src);
    r_p[i]  = __shfl(cell_p, src);
    r_m[i]  = __shfl(cell_m, src);
    r_n[i]  = __shfl(cell_n, src);
  }

  float xi = 0.f;
  if (lane < WPW && w0 + lane < (long long)W) {
    const float C00 = r_xx[0] + yy0 - 2.f * r_m[0];
    const float C01 = r_xx[0] + yy1 - 2.f * r_n[0];
    const float C10 = r_xx[1] + yy0 - 2.f * r_p[1];
    const float C11 = r_xx[1] + yy1 - 2.f * r_m[1];
    const float C12 = r_xx[1] + yy2 - 2.f * r_n[1];
    const float C21 = r_xx[2] + yy1 - 2.f * r_p[2];
    const float C22 = r_xx[2] + yy2 - 2.f * r_m[2];
    const float C23 = r_xx[2] + yy3 - 2.f * r_n[2];
    const float C32 = r_xx[3] + yy2 - 2.f * r_p[3];
    const float C33 = r_xx[3] + yy3 - 2.f * r_m[3];
    const float C34 = r_xx[3] + yy4 - 2.f * r_n[3];
    const float C43 = r_xx[4] + yy3 - 2.f * r_p[4];
    const float C44 = r_xx[4] + yy4 - 2.f * r_m[4];

    const float c11v = C00;
    const float c12v = C01 + c11v;
    const float c21v = C10 + c11v;
    const float c22v = C11 + fminf(fminf(c12v, c21v), c11v);
    const float c23v = C12 + fminf(c22v, c12v);
    const float c32v = C21 + fminf(c22v, c21v);
    const float c33v = C22 + fminf(fminf(c23v, c32v), c22v);
    const float c34v = C23 + fminf(c33v, c23v);
    const float c43v = C32 + fminf(c33v, c32v);
    const float c44v = C33 + fminf(fminf(c34v, c43v), c33v);
    const float c45v = C34 + fminf(c44v, c34v);
    const float c54v = C43 + fminf(c44v, c43v);
    const float c55v = C44 + fminf(fminf(c45v, c54v), c44v);

    xi = expf(ALPHA_C * sqrtf(fmaxf(c55v, 0.f)));
  }
  return xi;
}

__global__ __launch_bounds__(64, 2)
void softmin_dtw_kernel(const float* __restrict__ x, const float* __restrict__ S,
                        float* __restrict__ partials, long long Q, int W,
                        int NSP) {
  __shared__ __align__(16) float sX[2][SPAN_F];   // double-buffered span
  __shared__ __align__(16) float sS[512];         // this wave's S copy

  const int lane = threadIdx.x;                   // blockDim == 64
  const int bid = blockIdx.x;
  const long long spanStride = 250LL * WPW;       // 2750 floats

  // spans for this block: sp_k = bid + k*NBLK
  const int ns = (NSP > bid) ? (NSP - bid + NBLK - 1) / NBLK : 0;
  bool lastTail = false;
  if (ns > 0) {
    const long long bl = (long long)(bid + (ns - 1) * NBLK) * spanStride;
    lastTail = (bl + SPAN_F > Q);
  }
  const int nfull = ns - (lastTail ? 1 : 0);

  // ---- S copy: 2 direct-to-LDS loads ----
  __builtin_amdgcn_global_load_lds((gbl_ptr_t)(const void*)(S + 4 * lane),
                                   (lds_ptr_t)(void*)(&sS[0]), 16, 0, 0);
  if (lane < 61)
    __builtin_amdgcn_global_load_lds((gbl_ptr_t)(const void*)(S + 256 + 4 * lane),
                                     (lds_ptr_t)(void*)(&sS[256]), 16, 0, 0);

  // ---- prologue: stage span 0 into buffer 0 ----
  if (nfull > 0) {
    const long long b0 = (long long)bid * spanStride;
    #pragma unroll
    for (int r = 0; r < ROUNDS; ++r)
      __builtin_amdgcn_global_load_lds(
          (gbl_ptr_t)(const void*)(x + b0 + 256LL * r + 4LL * lane),
          (lds_ptr_t)(void*)(&sX[0][256 * r]), 16, 0, 0);
  }

  float yy0 = 0.f, yy1 = 0.f, yy2 = 0.f, yy3 = 0.f, yy4 = 0.f;
  bool yyDone = false;
  float xs = 0.f;

  // ---- main pipeline: stage(k+1) -> wait vmcnt(12) -> compute(k) ----
  for (int k = 0; k < nfull; ++k) {
    if (k + 1 < nfull) {
      const long long bn = (long long)(bid + (k + 1) * NBLK) * spanStride;
      float* dst = sX[(k + 1) & 1];
      #pragma unroll
      for (int r = 0; r < ROUNDS; ++r)
        __builtin_amdgcn_global_load_lds(
            (gbl_ptr_t)(const void*)(x + bn + 256LL * r + 4LL * lane),
            (lds_ptr_t)(void*)(dst + 256 * r), 16, 0, 0);
      // 12 newest (span k+1) stay in flight; span k (and S) are drained.
      asm volatile("s_waitcnt vmcnt(12)" ::: "memory");
    } else {
      asm volatile("s_waitcnt vmcnt(0)" ::: "memory");
    }
    __builtin_amdgcn_sched_barrier(0);

    if (!yyDone) {   // S is in LDS now; compute yy once per block
      float yyv = 0.f;
      if (lane < 5) {
        const float* sp = &sS[100 * lane];
        #pragma unroll
        for (int s = 0; s < 100; s += 4) {
          const float4 v = *reinterpret_cast<const float4*>(&sp[s]);
          yyv = fmaf(v.x, v.x,
                fmaf(v.y, v.y, fmaf(v.z, v.z, fmaf(v.w, v.w, yyv))));
        }
      }
      yy0 = __shfl(yyv, 0); yy1 = __shfl(yyv, 1); yy2 = __shfl(yyv, 2);
      yy3 = __shfl(yyv, 3); yy4 = __shfl(yyv, 4);
      yyDone = true;
    }

    const long long w0 = (long long)(bid + k * NBLK) * WPW;
    xs += span_body(sX[k & 1], sS, yy0, yy1, yy2, yy3, yy4, lane, w0, W);
  }

  // ---- tail span (at most one block hits this): unpipelined, guarded ----
  if (lastTail) {
    const long long bt = (long long)(bid + (ns - 1) * NBLK) * spanStride;
    float* xb = sX[nfull & 1];
    #pragma unroll
    for (int r = 0; r < ROUNDS; ++r) {
      const int idx = 256 * r + 4 * lane;
      const long long gp = bt + idx;
      float4 v;
      v.x = (gp     < Q) ? x[gp]     : 0.f;
      v.y = (gp + 1 < Q) ? x[gp + 1] : 0.f;
      v.z = (gp + 2 < Q) ? x[gp + 2] : 0.f;
      v.w = (gp + 3 < Q) ? x[gp + 3] : 0.f;
      *reinterpret_cast<float4*>(&xb[idx]) = v;
    }
    asm volatile("s_waitcnt vmcnt(0) lgkmcnt(0)" ::: "memory");
    __builtin_amdgcn_sched_barrier(0);

    if (!yyDone) {
      float yyv = 0.f;
      if (lane < 5) {
        const float* sp = &sS[100 * lane];
        #pragma unroll
        for (int s = 0; s < 100; s += 4) {
          const float4 v = *reinterpret_cast<const float4*>(&sp[s]);
          yyv = fmaf(v.x, v.x,
                fmaf(v.y, v.y, fmaf(v.z, v.z, fmaf(v.w, v.w, yyv))));
        }
      }
      yy0 = __shfl(yyv, 0); yy1 = __shfl(yyv, 1); yy2 = __shfl(yyv, 2);
      yy3 = __shfl(yyv, 3); yy4 = __shfl(yyv, 4);
      yyDone = true;
    }

    const long long w0 = (long long)(bid + (ns - 1) * NBLK) * WPW;
    xs += span_body(xb, sS, yy0, yy1, yy2, yy3, yy4, lane, w0, W);
  }

  // drain any leftover in-flight LDS writes (ns==0 blocks' S loads)
  asm volatile("s_waitcnt vmcnt(0)" ::: "memory");

  // ---- wave reduce accumulated xi, one plain store per block ----
  #pragma unroll
  for (int off = 32; off > 0; off >>= 1) xs += __shfl_down(xs, off);
  if (lane == 0) partials[bid] = xs;
}

__global__ __launch_bounds__(256)
void reduce_partials(const float* __restrict__ partials, float* __restrict__ out,
                     int n, float inv_W) {
  __shared__ float sR[4];
  const int tid = threadIdx.x;
  float a = 0.f;
  for (int i = tid; i < n; i += 256) a += partials[i];
  #pragma unroll
  for (int off = 32; off > 0; off >>= 1) a += __shfl_down(a, off);
  if ((tid & 63) == 0) sR[tid >> 6] = a;
  __syncthreads();
  if (tid == 0) out[0] = (sR[0] + sR[1] + sR[2] + sR[3]) * inv_W;
}

extern "C" void kernel_launch(void* const* d_in, const int* in_sizes, int n_in,
                              void* d_out, int out_size, void* d_ws, size_t ws_size,
                              hipStream_t stream) {
  const float* x = (const float*)d_in[0];
  const float* S = (const float*)d_in[1];
  float* out = (float*)d_out;
  float* partials = (float*)d_ws;

  const long long Q = in_sizes[0];
  const int L = in_sizes[1];   // 500
  const int step = L / 2;      // 250
  const long long n = Q - L;
  const int W = (int)((n + step - 1) / step);  // 79998
  const int NSP = (W + WPW - 1) / WPW;         // 7273 spans

  softmin_dtw_kernel<<<NBLK, 64, 0, stream>>>(x, S, partials, Q, W, NSP);
  reduce_partials<<<1, 256, 0, stream>>>(partials, out, NBLK,
                                         1.0f / (float)W);
}